// Round 1
// baseline (1899.731 us; speedup 1.0000x reference)
//
#include <hip/hip_runtime.h>

// Problem constants
#define NB 8
#define NT 1024
#define ND 768     // = 12*64
#define NH 12
#define NU 64
#define BT (NB*NT)   // 8192
#define SCALE32 ((float)0.03608439182435161)  // fp32(768^-0.5)
#define EPS32 1e-7f

// ---------------------------------------------------------------------------
// numpy baseline-SIMD (SSE2, no FMA) einsum dot over 64 contiguous elements:
// 4 accumulators stride-4, separate mul/add (rounded each), reduce
// (r0+r2)+(r1+r3). __f*_rn blocks hipcc contraction. BITWISE-IDENTICAL to R9.
// ---------------------------------------------------------------------------
__device__ __forceinline__ float dot64_np(const float* a, const float* b)
{
    float r[4];
#pragma unroll
    for (int j = 0; j < 4; j++) r[j] = __fmul_rn(a[j], b[j]);
#pragma unroll
    for (int i = 1; i < 16; i++)
#pragma unroll
        for (int j = 0; j < 4; j++)
            r[j] = __fadd_rn(r[j], __fmul_rn(a[i * 4 + j], b[i * 4 + j]));
    return __fadd_rn(__fadd_rn(r[0], r[2]), __fadd_rn(r[1], r[3]));
}

// ---------------------------------------------------------------------------
// Mask decode with byte/int32 layout sniff (mask is all-ones in practice).
// ---------------------------------------------------------------------------
__global__ __launch_bounds__(256) void mask_k(
    const unsigned char* __restrict__ mb, float* __restrict__ mf)
{
    __shared__ int cntOff, cntAll;
    if (threadIdx.x == 0) { cntOff = 0; cntAll = 0; }
    __syncthreads();
    int lo = 0, la = 0;
    for (int i = threadIdx.x; i < BT; i += 256)
        if (mb[i] != 0) { la++; if ((i & 3) != 0) lo++; }
    atomicAdd(&cntOff, lo);
    atomicAdd(&cntAll, la);
    __syncthreads();
    const bool int32mode = (cntOff == 0) && (cntAll != 0);
    if (int32mode) {
        const int* mi = (const int*)mb;
        for (int i = threadIdx.x; i < BT; i += 256)
            mf[i] = (mi[i] != 0) ? 1.f : 0.f;
    } else {
        for (int i = threadIdx.x; i < BT; i += 256)
            mf[i] = (mb[i] != 0) ? 1.f : 0.f;
    }
}

// ---------------------------------------------------------------------------
// OpenBLAS-mimic sgemm: C = A[8192x768] @ W[768x768] (+R elementwise after).
// kc=384 panel split preserved bitwise. LDS now b128-friendly: sA transposed
// to [k][m] (pad 68 keeps 16B alignment), microkernel does 2x ds_read_b128
// per kk instead of 8x b32. Arithmetic chains unchanged. grid (128,12).
// ---------------------------------------------------------------------------
__global__ __launch_bounds__(256) void gemmseq(
    const float* __restrict__ A, const float* __restrict__ W,
    const float* __restrict__ R, float* __restrict__ C)
{
    __shared__ float sA[64][68];   // [k][m], transposed, pad 68 (16B-aligned rows)
    __shared__ float sB[64][68];   // [k][n]

    const int t = threadIdx.x;
    const int mbase = blockIdx.x * 64;
    const int nbase = blockIdx.y * 64;
    const int m0 = (t >> 4) * 4;
    const int n0 = (t & 15) * 4;

    float acc[4][4], accA[4][4];
#pragma unroll
    for (int i = 0; i < 4; i++)
#pragma unroll
        for (int j = 0; j < 4; j++) { acc[i][j] = 0.f; accA[i][j] = 0.f; }

    for (int k0 = 0; k0 < 768; k0 += 64) {
        __syncthreads();
#pragma unroll
        for (int i = 0; i < 4; i++) {
            const int idx = t + i * 256;          // 0..1023
            const int mr = idx >> 4;              // 0..63
            const int k4 = (idx & 15) * 4;        // 0..60
            const float4 a4 = *(const float4*)&A[(size_t)(mbase + mr) * 768 + k0 + k4];
            sA[k4 + 0][mr] = a4.x;
            sA[k4 + 1][mr] = a4.y;
            sA[k4 + 2][mr] = a4.z;
            sA[k4 + 3][mr] = a4.w;
            *(float4*)&sB[mr][k4] =
                *(const float4*)&W[(size_t)(k0 + mr) * 768 + nbase + k4];
        }
        __syncthreads();

        for (int kk = 0; kk < 64; kk++) {
            float av[4], bv[4];
            *(float4*)&av[0] = *(const float4*)&sA[kk][m0];
            *(float4*)&bv[0] = *(const float4*)&sB[kk][n0];
#pragma unroll
            for (int i = 0; i < 4; i++)
#pragma unroll
                for (int j = 0; j < 4; j++)
                    acc[i][j] = fmaf(av[i], bv[j], acc[i][j]);
        }

        if (k0 + 64 == 384) {   // end of first kc panel (OpenBLAS kc=384)
#pragma unroll
            for (int i = 0; i < 4; i++)
#pragma unroll
                for (int j = 0; j < 4; j++) {
                    accA[i][j] = acc[i][j];
                    acc[i][j] = 0.f;
                }
        }
    }

#pragma unroll
    for (int i = 0; i < 4; i++)
#pragma unroll
        for (int j = 0; j < 4; j++) {
            const size_t idx = (size_t)(mbase + m0 + i) * 768 + nbase + n0 + j;
            float o = __fadd_rn(accA[i][j], acc[i][j]);  // C = panel0 + panel1
            if (R) o = __fadd_rn(o, R[idx]);             // np: out = tmp + x
            C[idx] = o;
        }
}

// ---------------------------------------------------------------------------
// Denominator: D[bh][t] = numpy pairwise_sum over s (8 base-128 blocks of
// 8 plain-add accumulators + tree). One THREAD per row, q in registers,
// k via wave-uniform scalar loads (readfirstlane-proven) — zero LDS.
// grid 768 x 128. Arithmetic bitwise-identical to R9.
// ---------------------------------------------------------------------------
__global__ __launch_bounds__(128) void denom_np(
    const float* __restrict__ Q, const float* __restrict__ K,
    const float* __restrict__ MF, float* __restrict__ D)
{
    const int gid = blockIdx.x * 128 + threadIdx.x;  // 0..98303
    const int bh = gid >> 10;                        // uniform per block
    const int row = gid & 1023;
    const int b = bh / NH, h = bh % NH;
    const int bh_u = __builtin_amdgcn_readfirstlane(bh);
    const int b_u = bh_u / NH, h_u = bh_u % NH;

    const float mq = MF[b * NT + row];

    float qr[64];
    const float4* qp = (const float4*)&Q[((size_t)(b * NT + row)) * ND + h * 64];
#pragma unroll
    for (int i = 0; i < 16; i++) *(float4*)&qr[i * 4] = qp[i];

    const float* Kb = &K[((size_t)(b_u * NT)) * ND + h_u * 64];
    const float* MFb = &MF[b_u * NT];

    float Bi[8];
    for (int c = 0; c < 8; c++) {
        float b8[8];
        for (int s = 0; s < 128; s++) {
            const int sg = c * 128 + s;
            const float dt = dot64_np(qr, Kb + (size_t)sg * ND); // uniform k
            float sc = __fmul_rn(dt, SCALE32);
            sc = __fmul_rn(sc, MFb[sg]);
            sc = __fmul_rn(sc, mq);
            const int j = s & 7;
            if (s < 8) b8[j] = sc;
            else       b8[j] = __fadd_rn(b8[j], sc);
        }
        Bi[c] = __fadd_rn(__fadd_rn(__fadd_rn(b8[0], b8[1]), __fadd_rn(b8[2], b8[3])),
                          __fadd_rn(__fadd_rn(b8[4], b8[5]), __fadd_rn(b8[6], b8[7])));
    }

    D[(size_t)bh * NT + row] = __fadd_rn(
        __fadd_rn(__fadd_rn(Bi[0], Bi[1]), __fadd_rn(Bi[2], Bi[3])),
        __fadd_rn(__fadd_rn(Bi[4], Bi[5]), __fadd_rn(Bi[6], Bi[7])));
}

// ---------------------------------------------------------------------------
// Attention out. One THREAD per row: q (64 regs), o[64] accumulators,
// k/v via wave-uniform scalar loads — zero LDS. Scores recomputed with the
// bitwise-identical dot/mask/scale/divide sequence; o[u] chains over s
// ascending 0..1023 exactly as R9. Self-aliased QA (each row read then
// written by its own thread only). grid 768 x 128.
// ---------------------------------------------------------------------------
__global__ __launch_bounds__(128) void attn_np(
    const float* __restrict__ K, const float* __restrict__ V,
    const float* __restrict__ D, const float* __restrict__ MF,
    float* __restrict__ QA)   // in: Q, out: A (self-aliased per row)
{
    const int gid = blockIdx.x * 128 + threadIdx.x;
    const int bh = gid >> 10;
    const int row = gid & 1023;
    const int b = bh / NH, h = bh % NH;
    const int bh_u = __builtin_amdgcn_readfirstlane(bh);
    const int b_u = bh_u / NH, h_u = bh_u % NH;

    const float mq = MF[b * NT + row];
    const float De = __fadd_rn(D[(size_t)bh * NT + row], EPS32);  // np: sum+eps

    float qr[64];
    const float4* qp = (const float4*)&QA[((size_t)(b * NT + row)) * ND + h * 64];
#pragma unroll
    for (int i = 0; i < 16; i++) *(float4*)&qr[i * 4] = qp[i];

    float o[64];
#pragma unroll
    for (int j = 0; j < 64; j++) o[j] = 0.f;

    const float* Kb = &K[((size_t)(b_u * NT)) * ND + h_u * 64];
    const float* Vb = &V[((size_t)(b_u * NT)) * ND + h_u * 64];
    const float* MFb = &MF[b_u * NT];

    for (int s = 0; s < NT; s++) {
        const float dt = dot64_np(qr, Kb + (size_t)s * ND);  // uniform k
        float sc = __fmul_rn(dt, SCALE32);
        sc = __fmul_rn(sc, MFb[s]);
        sc = __fmul_rn(sc, mq);
        const float p = __fdiv_rn(sc, De);
        const float* vp = Vb + (size_t)s * ND;               // uniform v
#pragma unroll
        for (int j = 0; j < 64; j++)
            o[j] = __fadd_rn(o[j], __fmul_rn(p, vp[j]));     // np SSE2 axpy
    }

    float4* op = (float4*)&QA[((size_t)(b * NT + row)) * ND + h * 64];
#pragma unroll
    for (int i = 0; i < 16; i++) op[i] = *(float4*)&o[i * 4];
}

// ---------------------------------------------------------------------------
// Row norm, numpy-faithful pairwise mean via ONE WAVE per row: lane (c,j)
// runs chain r8[j] of base-96 block c (12 plain adds); xor-butterfly
// reproduces ((r0+r1)+(r2+r3))+((r4+r5)+(r6+r7)) and the Ci tree bitwise
// (fp32 add is commutative). Then elementwise np-order normalize.
// grid 2048 x 256 (4 waves/block).
// ---------------------------------------------------------------------------
__global__ __launch_bounds__(256) void rownorm_np(
    float* __restrict__ Y, const float* __restrict__ gamma,
    const float* __restrict__ beta)
{
    const int wave = threadIdx.x >> 6, lane = threadIdx.x & 63;
    const int row = blockIdx.x * 4 + wave;
    float* yr = Y + (size_t)row * ND;
    const int c = lane >> 3, j = lane & 7;

    const float* a = yr + c * 96;
    float r = a[j];
#pragma unroll
    for (int i = 1; i < 12; i++) r = __fadd_rn(r, a[i * 8 + j]);

    // j-tree within base-96 block, then c-tree across blocks (bitwise = R9)
    r = __fadd_rn(r, __shfl_xor(r, 1, 64));
    r = __fadd_rn(r, __shfl_xor(r, 2, 64));
    r = __fadd_rn(r, __shfl_xor(r, 4, 64));
    r = __fadd_rn(r, __shfl_xor(r, 8, 64));
    r = __fadd_rn(r, __shfl_xor(r, 16, 64));
    r = __fadd_rn(r, __shfl_xor(r, 32, 64));

    const float m = __fdiv_rn(r, 768.0f);
    const float mpe = __fadd_rn(m, EPS32);

#pragma unroll
    for (int i = 0; i < 12; i++) {
        const int idx = i * 64 + lane;
        const float v = yr[idx];
        float o = __fsub_rn(v, m);
        o = __fmul_rn(gamma[idx], o);
        o = __fdiv_rn(o, mpe);
        o = __fadd_rn(o, beta[idx]);
        yr[idx] = o;
    }
}

// ---------------------------------------------------------------------------
extern "C" void kernel_launch(void* const* d_in, const int* in_sizes, int n_in,
                              void* d_out, int out_size, void* d_ws, size_t ws_size,
                              hipStream_t stream)
{
    (void)in_sizes; (void)n_in; (void)out_size; (void)ws_size;
    const float* x     = (const float*)d_in[0];
    const unsigned char* maskb = (const unsigned char*)d_in[1];
    const float* wq    = (const float*)d_in[2];
    const float* wk    = (const float*)d_in[3];
    const float* wv    = (const float*)d_in[4];
    const float* wf    = (const float*)d_in[5];
    const float* gamma = (const float*)d_in[6];
    const float* beta  = (const float*)d_in[7];

    float* ws = (float*)d_ws;
    float* MF = ws;                             // 8192
    float* D  = MF + BT;                        // 96*1024
    float* Q  = D + (size_t)96 * NT;            // 8192*768 (becomes A)
    float* K  = Q + (size_t)BT * ND;            // 8192*768
    float* V  = K + (size_t)BT * ND;            // 8192*768
    float* Y  = (float*)d_out;                  // total ws: 75.9 MB

    mask_k<<<1, 256, 0, stream>>>(maskb, MF);
    gemmseq<<<dim3(128, 12), 256, 0, stream>>>(x, wq, nullptr, Q);
    gemmseq<<<dim3(128, 12), 256, 0, stream>>>(x, wk, nullptr, K);
    gemmseq<<<dim3(128, 12), 256, 0, stream>>>(x, wv, nullptr, V);
    denom_np<<<768, 128, 0, stream>>>(Q, K, MF, D);
    attn_np<<<768, 128, 0, stream>>>(K, V, D, MF, Q);  // Q -> A
    gemmseq<<<dim3(128, 12), 256, 0, stream>>>(Q, wf, x, Y);
    rownorm_np<<<2048, 256, 0, stream>>>(Y, gamma, beta);
}

// Round 2
// 1750.885 us; speedup vs baseline: 1.0850x; 1.0850x over previous
//
#include <hip/hip_runtime.h>

// Problem constants
#define NB 8
#define NT 1024
#define ND 768     // = 12*64
#define NH 12
#define NU 64
#define BT (NB*NT)   // 8192
#define SCALE32 ((float)0.03608439182435161)  // fp32(768^-0.5)
#define EPS32 1e-7f

// ---------------------------------------------------------------------------
// numpy baseline-SIMD (SSE2, no FMA) einsum dot over 64 contiguous elements:
// 4 accumulators stride-4, separate mul/add (rounded each), reduce
// (r0+r2)+(r1+r3). __f*_rn blocks hipcc contraction. BITWISE-IDENTICAL to R9.
// ---------------------------------------------------------------------------
__device__ __forceinline__ float dot64_np(const float* a, const float* b)
{
    float r[4];
#pragma unroll
    for (int j = 0; j < 4; j++) r[j] = __fmul_rn(a[j], b[j]);
#pragma unroll
    for (int i = 1; i < 16; i++)
#pragma unroll
        for (int j = 0; j < 4; j++)
            r[j] = __fadd_rn(r[j], __fmul_rn(a[i * 4 + j], b[i * 4 + j]));
    return __fadd_rn(__fadd_rn(r[0], r[2]), __fadd_rn(r[1], r[3]));
}

// ---------------------------------------------------------------------------
// Mask decode with byte/int32 layout sniff (mask is all-ones in practice).
// ---------------------------------------------------------------------------
__global__ __launch_bounds__(256) void mask_k(
    const unsigned char* __restrict__ mb, float* __restrict__ mf)
{
    __shared__ int cntOff, cntAll;
    if (threadIdx.x == 0) { cntOff = 0; cntAll = 0; }
    __syncthreads();
    int lo = 0, la = 0;
    for (int i = threadIdx.x; i < BT; i += 256)
        if (mb[i] != 0) { la++; if ((i & 3) != 0) lo++; }
    atomicAdd(&cntOff, lo);
    atomicAdd(&cntAll, la);
    __syncthreads();
    const bool int32mode = (cntOff == 0) && (cntAll != 0);
    if (int32mode) {
        const int* mi = (const int*)mb;
        for (int i = threadIdx.x; i < BT; i += 256)
            mf[i] = (mi[i] != 0) ? 1.f : 0.f;
    } else {
        for (int i = threadIdx.x; i < BT; i += 256)
            mf[i] = (mb[i] != 0) ? 1.f : 0.f;
    }
}

// ---------------------------------------------------------------------------
// OpenBLAS-mimic sgemm: C = A[8192x768] @ W[768x768] (+R elementwise after).
// kc=384 panel split preserved bitwise. LDS now b128-friendly: sA transposed
// to [k][m] (pad 68 keeps 16B alignment), microkernel does 2x ds_read_b128
// per kk instead of 8x b32. Arithmetic chains unchanged. grid (128,12).
// ---------------------------------------------------------------------------
__global__ __launch_bounds__(256) void gemmseq(
    const float* __restrict__ A, const float* __restrict__ W,
    const float* __restrict__ R, float* __restrict__ C)
{
    __shared__ float sA[64][68];   // [k][m], transposed, pad 68 (16B-aligned rows)
    __shared__ float sB[64][68];   // [k][n]

    const int t = threadIdx.x;
    const int mbase = blockIdx.x * 64;
    const int nbase = blockIdx.y * 64;
    const int m0 = (t >> 4) * 4;
    const int n0 = (t & 15) * 4;

    float acc[4][4], accA[4][4];
#pragma unroll
    for (int i = 0; i < 4; i++)
#pragma unroll
        for (int j = 0; j < 4; j++) { acc[i][j] = 0.f; accA[i][j] = 0.f; }

    for (int k0 = 0; k0 < 768; k0 += 64) {
        __syncthreads();
#pragma unroll
        for (int i = 0; i < 4; i++) {
            const int idx = t + i * 256;          // 0..1023
            const int mr = idx >> 4;              // 0..63
            const int k4 = (idx & 15) * 4;        // 0..60
            const float4 a4 = *(const float4*)&A[(size_t)(mbase + mr) * 768 + k0 + k4];
            sA[k4 + 0][mr] = a4.x;
            sA[k4 + 1][mr] = a4.y;
            sA[k4 + 2][mr] = a4.z;
            sA[k4 + 3][mr] = a4.w;
            *(float4*)&sB[mr][k4] =
                *(const float4*)&W[(size_t)(k0 + mr) * 768 + nbase + k4];
        }
        __syncthreads();

        for (int kk = 0; kk < 64; kk++) {
            float av[4], bv[4];
            *(float4*)&av[0] = *(const float4*)&sA[kk][m0];
            *(float4*)&bv[0] = *(const float4*)&sB[kk][n0];
#pragma unroll
            for (int i = 0; i < 4; i++)
#pragma unroll
                for (int j = 0; j < 4; j++)
                    acc[i][j] = fmaf(av[i], bv[j], acc[i][j]);
        }

        if (k0 + 64 == 384) {   // end of first kc panel (OpenBLAS kc=384)
#pragma unroll
            for (int i = 0; i < 4; i++)
#pragma unroll
                for (int j = 0; j < 4; j++) {
                    accA[i][j] = acc[i][j];
                    acc[i][j] = 0.f;
                }
        }
    }

#pragma unroll
    for (int i = 0; i < 4; i++)
#pragma unroll
        for (int j = 0; j < 4; j++) {
            const size_t idx = (size_t)(mbase + m0 + i) * 768 + nbase + n0 + j;
            float o = __fadd_rn(accA[i][j], acc[i][j]);  // C = panel0 + panel1
            if (R) o = __fadd_rn(o, R[idx]);             // np: out = tmp + x
            C[idx] = o;
        }
}

// ---------------------------------------------------------------------------
// Denominator: D[bh][t] = numpy pairwise_sum over s (8 base-128 blocks of
// 8 plain-add accumulators + tree). One THREAD per row, q in registers,
// k via wave-uniform scalar loads (readfirstlane-proven) — zero LDS.
// grid 768 x 128. XCD-swizzled blockIdx: all 8 blocks of a bh group run on
// one XCD so the K slice is fetched once per XCD and L2-served 7x.
// Arithmetic bitwise-identical (pure index remap).
// ---------------------------------------------------------------------------
__global__ __launch_bounds__(128) void denom_np(
    const float* __restrict__ Q, const float* __restrict__ K,
    const float* __restrict__ MF, float* __restrict__ D)
{
    const int bid = blockIdx.x;
    const int lb  = (bid & 7) * 96 + (bid >> 3);     // XCD-grouped logical id
    const int gid = lb * 128 + threadIdx.x;          // 0..98303
    const int bh = gid >> 10;                        // uniform per block
    const int row = gid & 1023;
    const int b = bh / NH, h = bh % NH;
    const int bh_u = __builtin_amdgcn_readfirstlane(bh);
    const int b_u = bh_u / NH, h_u = bh_u % NH;

    const float mq = MF[b * NT + row];

    float qr[64];
    const float4* qp = (const float4*)&Q[((size_t)(b * NT + row)) * ND + h * 64];
#pragma unroll
    for (int i = 0; i < 16; i++) *(float4*)&qr[i * 4] = qp[i];

    const float* Kb = &K[((size_t)(b_u * NT)) * ND + h_u * 64];
    const float* MFb = &MF[b_u * NT];

    float Bi[8];
    for (int c = 0; c < 8; c++) {
        float b8[8];
        for (int s = 0; s < 128; s++) {
            const int sg = c * 128 + s;
            const float dt = dot64_np(qr, Kb + (size_t)sg * ND); // uniform k
            float sc = __fmul_rn(dt, SCALE32);
            sc = __fmul_rn(sc, MFb[sg]);
            sc = __fmul_rn(sc, mq);
            const int j = s & 7;
            if (s < 8) b8[j] = sc;
            else       b8[j] = __fadd_rn(b8[j], sc);
        }
        Bi[c] = __fadd_rn(__fadd_rn(__fadd_rn(b8[0], b8[1]), __fadd_rn(b8[2], b8[3])),
                          __fadd_rn(__fadd_rn(b8[4], b8[5]), __fadd_rn(b8[6], b8[7])));
    }

    D[(size_t)bh * NT + row] = __fadd_rn(
        __fadd_rn(__fadd_rn(Bi[0], Bi[1]), __fadd_rn(Bi[2], Bi[3])),
        __fadd_rn(__fadd_rn(Bi[4], Bi[5]), __fadd_rn(Bi[6], Bi[7])));
}

// ---------------------------------------------------------------------------
// Attention out. One THREAD per row: q (64 regs), o[64] accumulators,
// k/v via wave-uniform scalar loads — zero LDS. XCD-swizzled blockIdx
// (same mapping as denom_np): 8 blocks per bh co-located per XCD -> K/V
// slices stream through L2 with 8x reuse instead of 8x HBM re-fetch.
// Scores recomputed with the bitwise-identical dot/mask/scale/divide
// sequence; o[u] chains over s ascending 0..1023 exactly as R9.
// Self-aliased QA (each row read then written by its own thread only).
// grid 768 x 128.
// ---------------------------------------------------------------------------
__global__ __launch_bounds__(128) void attn_np(
    const float* __restrict__ K, const float* __restrict__ V,
    const float* __restrict__ D, const float* __restrict__ MF,
    float* __restrict__ QA)   // in: Q, out: A (self-aliased per row)
{
    const int bid = blockIdx.x;
    const int lb  = (bid & 7) * 96 + (bid >> 3);     // XCD-grouped logical id
    const int gid = lb * 128 + threadIdx.x;
    const int bh = gid >> 10;
    const int row = gid & 1023;
    const int b = bh / NH, h = bh % NH;
    const int bh_u = __builtin_amdgcn_readfirstlane(bh);
    const int b_u = bh_u / NH, h_u = bh_u % NH;

    const float mq = MF[b * NT + row];
    const float De = __fadd_rn(D[(size_t)bh * NT + row], EPS32);  // np: sum+eps

    float qr[64];
    const float4* qp = (const float4*)&QA[((size_t)(b * NT + row)) * ND + h * 64];
#pragma unroll
    for (int i = 0; i < 16; i++) *(float4*)&qr[i * 4] = qp[i];

    float o[64];
#pragma unroll
    for (int j = 0; j < 64; j++) o[j] = 0.f;

    const float* Kb = &K[((size_t)(b_u * NT)) * ND + h_u * 64];
    const float* Vb = &V[((size_t)(b_u * NT)) * ND + h_u * 64];
    const float* MFb = &MF[b_u * NT];

    for (int s = 0; s < NT; s++) {
        const float dt = dot64_np(qr, Kb + (size_t)s * ND);  // uniform k
        float sc = __fmul_rn(dt, SCALE32);
        sc = __fmul_rn(sc, MFb[s]);
        sc = __fmul_rn(sc, mq);
        const float p = __fdiv_rn(sc, De);
        const float* vp = Vb + (size_t)s * ND;               // uniform v
#pragma unroll
        for (int j = 0; j < 64; j++)
            o[j] = __fadd_rn(o[j], __fmul_rn(p, vp[j]));     // np SSE2 axpy
    }

    float4* op = (float4*)&QA[((size_t)(b * NT + row)) * ND + h * 64];
#pragma unroll
    for (int i = 0; i < 16; i++) op[i] = *(float4*)&o[i * 4];
}

// ---------------------------------------------------------------------------
// Row norm, numpy-faithful pairwise mean via ONE WAVE per row: lane (c,j)
// runs chain r8[j] of base-96 block c (12 plain adds); xor-butterfly
// reproduces ((r0+r1)+(r2+r3))+((r4+r5)+(r6+r7)) and the Ci tree bitwise
// (fp32 add is commutative). Then elementwise np-order normalize.
// grid 2048 x 256 (4 waves/block).
// ---------------------------------------------------------------------------
__global__ __launch_bounds__(256) void rownorm_np(
    float* __restrict__ Y, const float* __restrict__ gamma,
    const float* __restrict__ beta)
{
    const int wave = threadIdx.x >> 6, lane = threadIdx.x & 63;
    const int row = blockIdx.x * 4 + wave;
    float* yr = Y + (size_t)row * ND;
    const int c = lane >> 3, j = lane & 7;

    const float* a = yr + c * 96;
    float r = a[j];
#pragma unroll
    for (int i = 1; i < 12; i++) r = __fadd_rn(r, a[i * 8 + j]);

    // j-tree within base-96 block, then c-tree across blocks (bitwise = R9)
    r = __fadd_rn(r, __shfl_xor(r, 1, 64));
    r = __fadd_rn(r, __shfl_xor(r, 2, 64));
    r = __fadd_rn(r, __shfl_xor(r, 4, 64));
    r = __fadd_rn(r, __shfl_xor(r, 8, 64));
    r = __fadd_rn(r, __shfl_xor(r, 16, 64));
    r = __fadd_rn(r, __shfl_xor(r, 32, 64));

    const float m = __fdiv_rn(r, 768.0f);
    const float mpe = __fadd_rn(m, EPS32);

#pragma unroll
    for (int i = 0; i < 12; i++) {
        const int idx = i * 64 + lane;
        const float v = yr[idx];
        float o = __fsub_rn(v, m);
        o = __fmul_rn(gamma[idx], o);
        o = __fdiv_rn(o, mpe);
        o = __fadd_rn(o, beta[idx]);
        yr[idx] = o;
    }
}

// ---------------------------------------------------------------------------
extern "C" void kernel_launch(void* const* d_in, const int* in_sizes, int n_in,
                              void* d_out, int out_size, void* d_ws, size_t ws_size,
                              hipStream_t stream)
{
    (void)in_sizes; (void)n_in; (void)out_size; (void)ws_size;
    const float* x     = (const float*)d_in[0];
    const unsigned char* maskb = (const unsigned char*)d_in[1];
    const float* wq    = (const float*)d_in[2];
    const float* wk    = (const float*)d_in[3];
    const float* wv    = (const float*)d_in[4];
    const float* wf    = (const float*)d_in[5];
    const float* gamma = (const float*)d_in[6];
    const float* beta  = (const float*)d_in[7];

    float* ws = (float*)d_ws;
    float* MF = ws;                             // 8192
    float* D  = MF + BT;                        // 96*1024
    float* Q  = D + (size_t)96 * NT;            // 8192*768 (becomes A)
    float* K  = Q + (size_t)BT * ND;            // 8192*768
    float* V  = K + (size_t)BT * ND;            // 8192*768
    float* Y  = (float*)d_out;                  // total ws: 75.9 MB

    mask_k<<<1, 256, 0, stream>>>(maskb, MF);
    gemmseq<<<dim3(128, 12), 256, 0, stream>>>(x, wq, nullptr, Q);
    gemmseq<<<dim3(128, 12), 256, 0, stream>>>(x, wk, nullptr, K);
    gemmseq<<<dim3(128, 12), 256, 0, stream>>>(x, wv, nullptr, V);
    denom_np<<<768, 128, 0, stream>>>(Q, K, MF, D);
    attn_np<<<768, 128, 0, stream>>>(K, V, D, MF, Q);  // Q -> A
    gemmseq<<<dim3(128, 12), 256, 0, stream>>>(Q, wf, x, Y);
    rownorm_np<<<2048, 256, 0, stream>>>(Y, gamma, beta);
}